// Round 8
// baseline (257.044 us; speedup 1.0000x reference)
//
#include <hip/hip_runtime.h>
#include <hip/hip_bf16.h>
#include <math.h>

typedef __bf16 bf16;
typedef __attribute__((ext_vector_type(8))) __bf16 bf16x8;
typedef __attribute__((ext_vector_type(4))) __bf16 bf16x4;
typedef __attribute__((ext_vector_type(4))) float f32x4;

#define MFMA16(a,b,c) __builtin_amdgcn_mfma_f32_16x16x32_bf16(a,b,c,0,0,0)

// Problem constants
#define BATCH 2
#define SEQ   2048
#define DMODEL 768
#define NH    12
#define NKV   4
#define NREP  3
#define HD    64
#define FFDIM 2048
#define ROWS  (BATCH*SEQ)   // 4096

#define QSCALE 0.18033688011112042f
#define LOG2E  1.4426950408889634f

// Partial-drain barrier: wait until <=N of THIS wave's vmem ops outstanding,
// then barrier.  After all waves pass, every wave's covered loads are in LDS.
#define WB(N) asm volatile("s_waitcnt vmcnt(" #N ")\n\ts_barrier" ::: "memory")
#define BAR() asm volatile("s_barrier" ::: "memory")

__device__ __forceinline__ void gl2lds16(const bf16* g, bf16* l) {
  __builtin_amdgcn_global_load_lds(
      (const __attribute__((address_space(1))) void*)g,
      (__attribute__((address_space(3))) void*)l, 16, 0, 0);
}

// ---------------- fused fp32 -> bf16 convert (7 segs) + RoPE table (seg 7) ----------------
// Segs 4/5 (Wgate/Wup) are INTERLEAVED into one W' [4096][768]:
//   W'[64p + j]      = Wgate[32p + j]
//   W'[64p + 32 + j] = Wup  [32p + j]
// so the gu kernel pairs gate/up within one wave's 64-row strip of W'.
struct Cvt7 { const float* s[7]; bf16* d[7]; int n[7]; float* tab; };
__global__ __launch_bounds__(256) void cvt_all_kernel(Cvt7 c) {
  int seg = blockIdx.y;
  if (seg == 7) {
    int id = blockIdx.x * 256 + threadIdx.x;    // 65536 = 32 j * 2048 s
    int j = id >> 11, s = id & 2047;
    float inv = expf(-(float)j * (9.210340371976184f / 32.0f));
    float ang = (float)s * inv;
    c.tab[id] = cosf(ang);
    c.tab[65536 + id] = sinf(ang);
    return;
  }
  const float* __restrict__ src = c.s[seg];
  bf16* __restrict__ dst = c.d[seg];
  int n = c.n[seg];
  int stride = gridDim.x * 256;
  if (seg == 4 || seg == 5) {
    int up = (seg == 5) ? 32 : 0;
    for (int i = blockIdx.x * 256 + threadIdx.x; i < n; i += stride) {
      int rg = i / 768, cc = i - rg * 768;
      int drow = ((rg >> 5) << 6) + (rg & 31) + up;
      dst[(size_t)drow * 768 + cc] = (bf16)src[i];
    }
    return;
  }
  for (int i = blockIdx.x * 256 + threadIdx.x; i < n; i += stride)
    dst[i] = (bf16)src[i];
}

// ---------------- RMSNorm (vectorized f32x4, 192 threads) ----------------
__global__ __launch_bounds__(192) void rmsnorm_kernel(const float* __restrict__ x,
    const float* __restrict__ g, bf16* __restrict__ out) {
  int row = blockIdx.x;
  const float* xr = x + (size_t)row * DMODEL;
  int t = threadIdx.x;
  f32x4 v = *(const f32x4*)(xr + t * 4);
  float ss = v[0] * v[0] + v[1] * v[1] + v[2] * v[2] + v[3] * v[3];
  #pragma unroll
  for (int off = 32; off; off >>= 1) ss += __shfl_xor(ss, off, 64);
  __shared__ float red[3];
  if ((t & 63) == 0) red[t >> 6] = ss;
  __syncthreads();
  float total = red[0] + red[1] + red[2];
  float norm = sqrtf(total) * 0.03608439182435161f;  // 768^-0.5
  float sc = 1.0f / (norm + 1e-6f);
  f32x4 gv = *(const f32x4*)(g + t * 4);
  bf16x4 o;
  #pragma unroll
  for (int i = 0; i < 4; ++i) o[i] = (bf16)(gv[i] * v[i] * sc);
  *(bf16x4*)(out + (size_t)row * DMODEL + t * 4) = o;
}

// ---------------- Output GEMM 64x64, in-block split-K=2, 8 waves ----------------
__global__ __launch_bounds__(512, 6) void gemm_out_kernel(const bf16* __restrict__ A,
    const bf16* __restrict__ B, float* __restrict__ C, const float* __restrict__ R,
    int N, int K) {
  __shared__ __align__(16) bf16 At[2][3][64 * 32];   // 24KB
  __shared__ __align__(16) bf16 Bt[2][3][64 * 32];   // 24KB
  int t = threadIdx.x;
  int g = t >> 8;                    // K-group (0: lower half, 1: upper half)
  int tt = t & 255;                  // thread-in-group
  int lane = t & 63;
  int w = (t >> 6) & 3;              // wave-in-group
  int l15 = lane & 15, lq = lane >> 4;
  int wrow = (w >> 1) * 32, wcol = (w & 1) * 32;

  // XCD-chunked remap: 768 wgs = 8 XCDs x 96; same-A row-strips go to one XCD.
  int flat = blockIdx.y * 12 + blockIdx.x;
  int f2 = (flat & 7) * 96 + (flat >> 3);
  int col0 = (f2 % 12) * 64, row0 = (f2 / 12) * 64;

  const int KH = K >> 1;
  const int NS = KH / 32;            // 12 (Wo, K=768) or 32 (Wdown, K=2048)
  const bf16* Ag = A + (size_t)(row0 + (tt >> 2)) * K + g * KH + (tt & 3) * 8;
  const bf16* Bg = B + (size_t)(col0 + (tt >> 2)) * K + g * KH + (tt & 3) * 8;

  #pragma unroll
  for (int s = 0; s < 2; ++s) {
    gl2lds16(Ag + s * 32, At[g][s] + tt * 8);
    gl2lds16(Bg + s * 32, Bt[g][s] + tt * 8);
  }

  f32x4 zero = {0.f, 0.f, 0.f, 0.f};
  f32x4 acc[2][2];
  #pragma unroll
  for (int m = 0; m < 2; ++m)
    #pragma unroll
    for (int n = 0; n < 2; ++n) acc[m][n] = zero;

  #define OG_COMPUTE(slot) do {                                              \
    const bf16* at = At[g][slot]; const bf16* bt = Bt[g][slot];              \
    bf16x8 af[2], bb[2];                                                     \
    _Pragma("unroll")                                                        \
    for (int m = 0; m < 2; ++m)                                              \
      af[m] = *(const bf16x8*)(at + (wrow + m * 16 + l15) * 32 + lq * 8);    \
    _Pragma("unroll")                                                        \
    for (int n = 0; n < 2; ++n)                                              \
      bb[n] = *(const bf16x8*)(bt + (wcol + n * 16 + l15) * 32 + lq * 8);    \
    _Pragma("unroll")                                                        \
    for (int m = 0; m < 2; ++m)                                              \
      _Pragma("unroll")                                                      \
      for (int n = 0; n < 2; ++n)                                            \
        acc[m][n] = MFMA16(af[m], bb[n], acc[m][n]);                         \
  } while (0)

  int slot = 0;
  for (int k = 0; k < NS - 1; ++k) {
    WB(2);                        // stage k resident; stage k+1 may be in flight
    if (k + 2 < NS) {
      int ks = (k + 2) * 32;
      int ws = slot + 2; if (ws >= 3) ws -= 3;   // (k+2)%3 == (k-1)%3
      gl2lds16(Ag + ks, At[g][ws] + tt * 8);
      gl2lds16(Bg + ks, Bt[g][ws] + tt * 8);
    }
    OG_COMPUTE(slot);
    slot = (slot == 2) ? 0 : slot + 1;
  }
  WB(0);
  OG_COMPUTE(slot);
  #undef OG_COMPUTE

  // ---- combine K-halves through LDS overlay (16KB over At), then store ----
  __syncthreads();                  // all LDS reads for compute complete
  float* Cl = (float*)&At[0][0][0];
  if (g == 1) {
    #pragma unroll
    for (int m = 0; m < 2; ++m)
      #pragma unroll
      for (int n = 0; n < 2; ++n)
        #pragma unroll
        for (int r = 0; r < 4; ++r)
          Cl[(wrow + m * 16 + lq * 4 + r) * 64 + wcol + n * 16 + l15] = acc[m][n][r];
  }
  __syncthreads();
  if (g == 0) {
    #pragma unroll
    for (int m = 0; m < 2; ++m)
      #pragma unroll
      for (int n = 0; n < 2; ++n)
        #pragma unroll
        for (int r = 0; r < 4; ++r) {
          int row = wrow + m * 16 + lq * 4 + r;
          int col = wcol + n * 16 + l15;
          size_t idx = (size_t)(row0 + row) * N + col0 + col;
          C[idx] = acc[m][n][r] + Cl[row * 64 + col] + R[idx];
        }
  }
}

// ---------------- QKV GEMM + fused RoPE epilogue: ring-4, single barrier ----------------
__global__ __launch_bounds__(256) void gemm_qkv_kernel(const bf16* __restrict__ A,
    const bf16* __restrict__ Wcat, const float* __restrict__ tab,
    bf16* __restrict__ Qh, bf16* __restrict__ Kh, bf16* __restrict__ Vt) {
  __shared__ __align__(16) bf16 At[4][64 * 32];
  __shared__ __align__(16) bf16 Bt[4][128 * 32];
  const int K = DMODEL;
  int t = threadIdx.x, lane = t & 63, wave = t >> 6;
  int l15 = lane & 15, lq = lane >> 4;
  int wrow = (wave >> 1) * 32, wcol = (wave & 1) * 64;
  int row0 = blockIdx.y * 64, col0 = blockIdx.x * 128;
  const bf16* Ag  = A + (size_t)(row0 + (t >> 2)) * K + (t & 3) * 8;
  const bf16* Bg0 = Wcat + (size_t)(col0 + (t >> 2)) * K + (t & 3) * 8;
  const bf16* Bg1 = Bg0 + (size_t)64 * K;
  const int NS = K / 32;   // 24

  #pragma unroll
  for (int s = 0; s < 3; ++s) {
    int ks = s * 32;
    gl2lds16(Ag + ks,  At[s] + t * 8);
    gl2lds16(Bg0 + ks, Bt[s] + t * 8);
    gl2lds16(Bg1 + ks, Bt[s] + 2048 + t * 8);
  }

  f32x4 zero = {0.f, 0.f, 0.f, 0.f};
  f32x4 acc[2][4];
  #pragma unroll
  for (int m = 0; m < 2; ++m)
    #pragma unroll
    for (int n = 0; n < 4; ++n) acc[m][n] = zero;

  #define QK_COMPUTE(slot) do {                                              \
    const bf16* at = At[slot]; const bf16* bt = Bt[slot];                    \
    bf16x8 af[2], bfr[4];                                                    \
    _Pragma("unroll")                                                        \
    for (int m = 0; m < 2; ++m)                                              \
      af[m] = *(const bf16x8*)(at + (wrow + m * 16 + l15) * 32 + lq * 8);    \
    _Pragma("unroll")                                                        \
    for (int n = 0; n < 4; ++n)                                              \
      bfr[n] = *(const bf16x8*)(bt + (wcol + n * 16 + l15) * 32 + lq * 8);   \
    _Pragma("unroll")                                                        \
    for (int m = 0; m < 2; ++m)                                              \
      _Pragma("unroll")                                                      \
      for (int n = 0; n < 4; ++n)                                            \
        acc[m][n] = MFMA16(af[m], bfr[n], acc[m][n]);                        \
  } while (0)

  for (int k = 0; k < NS - 2; ++k) {
    WB(6);
    if (k + 3 < NS) {
      int ks = (k + 3) * 32;
      int ws = (k + 3) & 3;
      gl2lds16(Ag + ks,  At[ws] + t * 8);
      gl2lds16(Bg0 + ks, Bt[ws] + t * 8);
      gl2lds16(Bg1 + ks, Bt[ws] + 2048 + t * 8);
    }
    QK_COMPUTE(k & 3);
  }
  WB(3);
  QK_COMPUTE((NS - 2) & 3);
  WB(0);
  QK_COMPUTE((NS - 1) & 3);
  #undef QK_COMPUTE

  // ---- epilogue: RoPE (Q,K) / transpose-store (V) ----
  int b = row0 >> 11;
  int s0 = (row0 & 2047) + wrow + lq * 4;
  int colw = col0 + wcol;
  if (colw < 768) {
    int h = colw >> 6;
    f32x4 cv[2][2], sv[2][2];
    #pragma unroll
    for (int m = 0; m < 2; ++m)
      #pragma unroll
      for (int jh = 0; jh < 2; ++jh) {
        const float* cp = tab + (jh * 16 + l15) * 2048 + s0 + m * 16;
        cv[m][jh] = *(const f32x4*)cp;
        sv[m][jh] = *(const f32x4*)(cp + 65536);
      }
    #pragma unroll
    for (int m = 0; m < 2; ++m)
      #pragma unroll
      for (int n = 0; n < 4; ++n) {
        float sgn = (n < 2) ? -1.f : 1.f;
        #pragma unroll
        for (int r = 0; r < 4; ++r) {
          float c = cv[m][n & 1][r], si = sv[m][n & 1][r];
          float rp = (acc[m][n][r] * c + sgn * acc[m][n ^ 2][r] * si) * QSCALE;
          Qh[((size_t)(b * NH + h) * SEQ + s0 + m * 16 + r) * 64 + n * 16 + l15] = (bf16)rp;
        }
      }
  } else if (colw < 1024) {
    int kh = (colw - 768) >> 6;
    f32x4 cv[2][2], sv[2][2];
    #pragma unroll
    for (int m = 0; m < 2; ++m)
      #pragma unroll
      for (int jh = 0; jh < 2; ++jh) {
        const float* cp = tab + (jh * 16 + l15) * 2048 + s0 + m * 16;
        cv[m][jh] = *(const f32x4*)cp;
        sv[m][jh] = *(const f32x4*)(cp + 65536);
      }
    #pragma unroll
    for (int m = 0; m < 2; ++m)
      #pragma unroll
      for (int n = 0; n < 4; ++n) {
        float sgn = (n < 2) ? -1.f : 1.f;
        #pragma unroll
        for (int r = 0; r < 4; ++r) {
          float c = cv[m][n & 1][r], si = sv[m][n & 1][r];
          float rp = acc[m][n][r] * c + sgn * acc[m][n ^ 2][r] * si;
          Kh[((size_t)(b * NKV + kh) * SEQ + s0 + m * 16 + r) * 64 + n * 16 + l15] = (bf16)rp;
        }
      }
  } else {
    int vh = (colw - 1024) >> 6;
    #pragma unroll
    for (int m = 0; m < 2; ++m)
      #pragma unroll
      for (int n = 0; n < 4; ++n) {
        bf16x4 pv;
        #pragma unroll
        for (int r = 0; r < 4; ++r) pv[r] = (bf16)acc[m][n][r];
        *(bf16x4*)(Vt + ((size_t)(b * NKV + vh) * 64 + n * 16 + l15) * SEQ + s0 + m * 16) = pv;
      }
  }
}

// ---------------- Gate/up fused GEMM + silu: 128x128, 4 waves (64x64), ring-3 ----------------
// m97-class structure with all measured-positive elements: interleaved W'
// (2 staged matrices, 4 gl2lds/thread/step), single-barrier ring-3 with
// counted WB(4) (stage k+1 stays in flight across barrier), FRAGMENT-MAJOR
// LDS (conflict-free ds_read by construction), 3 blocks/CU (48KB LDS),
// grid 32x32=1024 XCD-remapped.  Wave tile 64x64: 8 ds_read : 16 MFMA.
__global__ __launch_bounds__(256, 2) void gemm_gu_kernel(const bf16* __restrict__ A,
    const bf16* __restrict__ W, bf16* __restrict__ H) {
  __shared__ __align__(16) bf16 Als[3][128 * 32];   // 24KB
  __shared__ __align__(16) bf16 Bls[3][128 * 32];   // 24KB
  const int NS = 24;                 // 768 / 32
  int t = threadIdx.x, lane = t & 63, wave = t >> 6;
  int l15 = lane & 15, lq = lane >> 4;
  int lfrag = l15 * 32 + lq * 8;     // lane offset within a fragment group
  int wm = wave >> 1, wn = wave & 1;

  // XCD-chunked remap: 1024 blocks = 8 XCDs x 128.
  int flat = blockIdx.y * 32 + blockIdx.x;
  int f2 = (flat & 7) * 128 + (flat >> 3);
  int colb = f2 & 31, rowb = f2 >> 5;
  int row0 = rowb * 128, col0w = colb * 128;

  // Fragment-major stage of a 128x32 tile (512 16B-chunks; thread t loads
  // chunks t and t+256).  chunk c -> global row (c>>6)*16 + ((c>>2)&15),
  // k-slice (c&3)*8.  ds_read for (m2=row-group, l15, lq) hits chunk
  // m2*64 + l15*4 + lq -> 64 consecutive chunks per wave = conflict-free.
  #define STAGE(G, orow, L, slot, j) do {                                    \
    bf16* lb = (L)[slot] + t * 8;                                            \
    const bf16* gb = (G) + (size_t)((orow) + ((t >> 6) << 4)                 \
                   + ((t >> 2) & 15)) * 768 + (j) * 32 + (t & 3) * 8;        \
    gl2lds16(gb, lb);                                                        \
    gl2lds16(gb + (size_t)64 * 768, lb + 2048);                              \
  } while (0)

  // Prologue: tiles 0 and 1 (8 loads).
  STAGE(A, row0,  Als, 0, 0);  STAGE(W, col0w, Bls, 0, 0);
  STAGE(A, row0,  Als, 1, 1);  STAGE(W, col0w, Bls, 1, 1);

  f32x4 zero = {0.f, 0.f, 0.f, 0.f};
  f32x4 acc[4][4];
  #pragma unroll
  for (int m = 0; m < 4; ++m)
    #pragma unroll
    for (int n = 0; n < 4; ++n) acc[m][n] = zero;

  #define GU_COMPUTE(slot) do {                                              \
    const bf16* aB = Als[slot] + lfrag;                                      \
    const bf16* bB = Bls[slot] + lfrag;                                      \
    bf16x8 af[4], bb[4];                                                     \
    _Pragma("unroll")                                                        \
    for (int m = 0; m < 4; ++m)                                              \
      af[m] = *(const bf16x8*)(aB + (wm * 4 + m) * 512);                     \
    _Pragma("unroll")                                                        \
    for (int n = 0; n < 4; ++n)                                              \
      bb[n] = *(const bf16x8*)(bB + (wn * 4 + n) * 512);                     \
    _Pragma("unroll")                                                        \
    for (int m = 0; m < 4; ++m)                                              \
      _Pragma("unroll")                                                      \
      for (int n = 0; n < 4; ++n)                                            \
        acc[m][n] = MFMA16(af[m], bb[n], acc[m][n]);                         \
  } while (0)

  int slot = 0;
  for (int k = 0; k < NS - 1; ++k) {
    WB(4);                        // stage k resident; stage k+1 (4 loads) in flight
    if (k + 2 < NS) {
      int ws = slot + 2; if (ws >= 3) ws -= 3;   // (k+2)%3 == (k-1)%3
      STAGE(A, row0,  Als, ws, k + 2);
      STAGE(W, col0w, Bls, ws, k + 2);
    }
    GU_COMPUTE(slot);
    slot = (slot == 2) ? 0 : slot + 1;
  }
  WB(0);
  GU_COMPUTE(slot);
  #undef GU_COMPUTE
  #undef STAGE

  // ---- epilogue: silu(gate)*up.  Wave covers W' 64-group p = colb*2+wn:
  // n in {0,1} = gate rows 32p+n*16+l15, n in {2,3} = matching up rows.
  int hc0 = colb * 64 + wn * 32;
  #pragma unroll
  for (int m = 0; m < 4; ++m)
    #pragma unroll
    for (int n = 0; n < 2; ++n)
      #pragma unroll
      for (int r = 0; r < 4; ++r) {
        int row = row0 + wm * 64 + m * 16 + lq * 4 + r;
        int col = hc0 + n * 16 + l15;
        float g = acc[m][n][r], u = acc[m][n + 2][r];
        float sg = g / (1.f + __builtin_amdgcn_exp2f(-g * LOG2E));
        H[(size_t)row * FFDIM + col] = (bf16)(sg * u);
      }
}

// ---------------- Flash attention: fragment-major K/V LDS (conflict-free) ----------------
__global__ __launch_bounds__(256) void attn_kernel(const bf16* __restrict__ Qh,
    const bf16* __restrict__ Kh, const bf16* __restrict__ Vt, bf16* __restrict__ out) {
  __shared__ __align__(16) bf16 Kl0[2][64 * 32];
  __shared__ __align__(16) bf16 Kl1[2][64 * 32];
  __shared__ __align__(16) bf16 Vl0[2][64 * 32];
  __shared__ __align__(16) bf16 Vl1[2][64 * 32];
  __shared__ __align__(16) bf16 P[4][16 * 80];

  int idx = blockIdx.x;
  int qt = 31 - (idx / 24);                      // LPT: heaviest first
  int bh = idx % 24;
  int q0blk = qt * 64;
  int b = bh / NH, h = bh % NH;
  int kvh = h / NREP;
  int t = threadIdx.x;
  int lane = t & 63, wave = t >> 6;
  int l15 = lane & 15, lq = lane >> 4;
  int qw = q0blk + wave * 16;
  const bf16* Qb = Qh + (size_t)(b * NH + h) * SEQ * 64;
  const bf16* Kb = Kh + (size_t)(b * NKV + kvh) * SEQ * 64;
  const bf16* Vb = Vt + (size_t)(b * NKV + kvh) * 64 * SEQ;

  bf16x8 bq0 = *(const bf16x8*)(Qb + (size_t)(qw + l15) * 64 + lq * 8);
  bf16x8 bq1 = *(const bf16x8*)(Qb + (size_t)(qw + l15) * 64 + 32 + lq * 8);

  // fragment-major staging source: thread t covers row srow, k-slice scol
  int srow = (t >> 6) * 16 + ((t >> 2) & 15);
  int scol = (t & 3) * 8;
  const bf16* Kg = Kb + (size_t)srow * 64 + scol;
  const bf16* Vg = Vb + (size_t)srow * SEQ + scol;
  bf16* Pw = P[wave];
  int Pwq = l15 * 80, lq8 = lq * 8, lq4 = lq * 4;
  int lfrag = l15 * 32 + lq8;                    // fragment-major read offset
  const int NS = qt + 1;                         // 64-key steps

  #pragma unroll
  for (int s = 0; s < 2; ++s) {
    int ks = (s < NS ? s : NS - 1) * 64;
    gl2lds16(Kg + (size_t)ks * 64,      Kl0[s] + t * 8);
    gl2lds16(Kg + (size_t)ks * 64 + 32, Kl1[s] + t * 8);
    gl2lds16(Vg + ks,                   Vl0[s] + t * 8);
    gl2lds16(Vg + ks + 32,              Vl1[s] + t * 8);
  }

  f32x4 zero = {0.f, 0.f, 0.f, 0.f};
  f32x4 o[4];
  o[0] = zero; o[1] = zero; o[2] = zero; o[3] = zero;
  float l_r = 0.f;

  #define ATTN_STEP(kk, slot) do {                                           \
    int k0 = (kk) * 64;                                                      \
    const bf16* kl0 = Kl0[slot]; const bf16* kl1 = Kl1[slot];                \
    const bf16* vl0 = Vl0[slot]; const bf16* vl1 = Vl1[slot];                \
    f32x4 s[4];                                                              \
    _Pragma("unroll")                                                        \
    for (int c = 0; c < 4; ++c) {                                            \
      bf16x8 ak0 = *(const bf16x8*)(kl0 + c * 512 + lfrag);                  \
      bf16x8 ak1 = *(const bf16x8*)(kl1 + c * 512 + lfrag);                  \
      s[c] = zero;                                                           \
      s[c] = MFMA16(ak0, bq0, s[c]);                                         \
      s[c] = MFMA16(ak1, bq1, s[c]);                                         \
    }                                                                        \
    if (k0 + 63 > qw) {                                                      \
      int qmk = qw + l15 - k0 - lq4;                                         \
      _Pragma("unroll")                                                      \
      for (int c = 0; c < 4; ++c)                                            \
        _Pragma("unroll")                                                    \
        for (int r = 0; r < 4; ++r)                                          \
          if (c * 16 + r > qmk) s[c][r] = -INFINITY;                         \
    }                                                                        \
    _Pragma("unroll")                                                        \
    for (int c = 0; c < 4; ++c) {                                            \
      bf16x4 pe;                                                             \
      _Pragma("unroll")                                                      \
      for (int r = 0; r < 4; ++r) {                                          \
        float e = __builtin_amdgcn_exp2f(s[c][r]);                           \
        l_r += e;                                                            \
        pe[r] = (bf16)e;                                                     \
      }                                                                      \
      *(bf16x4*)(Pw + Pwq + c * 16 + lq4) = pe;                              \
    }                                                                        \
    bf16x8 bp0 = *(const bf16x8*)(Pw + Pwq + lq8);                           \
    bf16x8 bp1 = *(const bf16x8*)(Pw + Pwq + 32 + lq8);                      \
    _Pragma("unroll")                                                        \
    for (int n = 0; n < 4; ++n) {                                            \
      bf16x8 av0 = *(const bf16x8*)(vl0 + n * 512 + lfrag);                  \
      bf16x8 av1 = *(const bf16x8*)(vl1 + n * 512 + lfrag);                  \
      o[n] = MFMA16(av0, bp0, o[n]);                                         \
      o[n] = MFMA16(av1, bp1, o[n]);                                         \
    }                                                                        \
  } while (0)

  for (int k = 0; k < NS - 1; ++k) {
    WB(4);                        // stage k resident (1 newer stage = 4 loads in flight)
    ATTN_STEP(k, k & 1);
    BAR();
    if (k <= NS - 3) {
      int ks = (k + 2) * 64;
      gl2lds16(Kg + (size_t)ks * 64,      Kl0[k & 1] + t * 8);
      gl2lds16(Kg + (size_t)ks * 64 + 32, Kl1[k & 1] + t * 8);
      gl2lds16(Vg + ks,                   Vl0[k & 1] + t * 8);
      gl2lds16(Vg + ks + 32,              Vl1[k & 1] + t * 8);
    }
  }
  {
    WB(0);
    ATTN_STEP(NS - 1, (NS - 1) & 1);
  }
  #undef ATTN_STEP

  float lt = l_r;
  lt += __shfl_xor(lt, 16, 64);
  lt += __shfl_xor(lt, 32, 64);
  float inv = 1.f / lt;
  int q = qw + l15;
  bf16* orow = out + (size_t)(b * SEQ + q) * DMODEL + h * 64;
  #pragma unroll
  for (int n = 0; n < 4; ++n) {
    bf16x4 po;
    #pragma unroll
    for (int r = 0; r < 4; ++r) po[r] = (bf16)(o[n][r] * inv);
    *(bf16x4*)(orow + n * 16 + lq4) = po;
  }
}

extern "C" void kernel_launch(void* const* d_in, const int* in_sizes, int n_in,
                              void* d_out, int out_size, void* d_ws, size_t ws_size,
                              hipStream_t stream) {
  const float* x     = (const float*)d_in[0];
  const float* Wq    = (const float*)d_in[1];
  const float* Wk    = (const float*)d_in[2];
  const float* Wv    = (const float*)d_in[3];
  const float* Wo    = (const float*)d_in[4];
  const float* Wgate = (const float*)d_in[5];
  const float* Wup   = (const float*)d_in[6];
  const float* Wdown = (const float*)d_in[7];
  const float* g1    = (const float*)d_in[8];
  const float* g2    = (const float*)d_in[9];
  float* out = (float*)d_out;

  char* ws = (char*)d_ws;
  size_t off = 0;
  auto alloc = [&](size_t bytes) { size_t o = off; off += (bytes + 255) & ~(size_t)255; return o; };
  size_t o_tab  = alloc((size_t)2 * 32 * 2048 * 4);          // 512KB cos/sin
  size_t o_x1   = alloc((size_t)4096 * 768 * 4);
  size_t o_xn   = alloc((size_t)4096 * 768 * 2);
  size_t o_Qh   = alloc((size_t)2 * 12 * 2048 * 64 * 2);
  size_t o_Kh   = alloc((size_t)2 * 4 * 2048 * 64 * 2);
  size_t o_Vt   = alloc((size_t)2 * 4 * 64 * 2048 * 2);
  size_t o_ao   = alloc((size_t)4096 * 768 * 2);
  size_t o_H    = alloc((size_t)4096 * 2048 * 2);
  size_t o_Wcat = alloc((size_t)1280 * 768 * 2);
  size_t o_Wo   = alloc((size_t)768 * 768 * 2);
  size_t o_Wgu  = alloc((size_t)4096 * 768 * 2);
  size_t o_Wdn  = alloc((size_t)768 * 2048 * 2);
  if (ws_size < off) return;

  float* tab  = (float*)(ws + o_tab);
  float* fx1  = (float*)(ws + o_x1);
  bf16* bxn   = (bf16*)(ws + o_xn);
  bf16* bQh   = (bf16*)(ws + o_Qh);
  bf16* bKh   = (bf16*)(ws + o_Kh);
  bf16* bVt   = (bf16*)(ws + o_Vt);
  bf16* bao   = (bf16*)(ws + o_ao);
  bf16* bH    = (bf16*)(ws + o_H);
  bf16* bWcat = (bf16*)(ws + o_Wcat);
  bf16* bWo   = (bf16*)(ws + o_Wo);
  bf16* bWgu  = (bf16*)(ws + o_Wgu);
  bf16* bWdn  = (bf16*)(ws + o_Wdn);

  Cvt7 c;
  c.s[0] = Wq;    c.d[0] = bWcat;              c.n[0] = 768 * 768;
  c.s[1] = Wk;    c.d[1] = bWcat + 768 * 768;  c.n[1] = 256 * 768;
  c.s[2] = Wv;    c.d[2] = bWcat + 1024 * 768; c.n[2] = 256 * 768;
  c.s[3] = Wo;    c.d[3] = bWo;                c.n[3] = 768 * 768;
  c.s[4] = Wgate; c.d[4] = bWgu;               c.n[4] = 2048 * 768;   // interleaved
  c.s[5] = Wup;   c.d[5] = bWgu;               c.n[5] = 2048 * 768;   // interleaved
  c.s[6] = Wdown; c.d[6] = bWdn;               c.n[6] = 768 * 2048;
  c.tab = tab;
  cvt_all_kernel<<<dim3(256, 8), 256, 0, stream>>>(c);

  // Attention sublayer
  rmsnorm_kernel<<<4096, 192, 0, stream>>>(x, g1, bxn);
  gemm_qkv_kernel<<<dim3(10, 64), 256, 0, stream>>>(bxn, bWcat, tab, bQh, bKh, bVt);
  attn_kernel<<<dim3(768), 256, 0, stream>>>(bQh, bKh, bVt, bao);
  gemm_out_kernel<<<dim3(12, 64), 512, 0, stream>>>(bao, bWo, fx1, x, 768, 768);

  // FFN sublayer
  rmsnorm_kernel<<<4096, 192, 0, stream>>>(fx1, g2, bxn);
  gemm_gu_kernel<<<dim3(32, 32), 256, 0, stream>>>(bxn, bWgu, bH);
  gemm_out_kernel<<<dim3(12, 64), 512, 0, stream>>>(bH, bWdn, out, fx1, 768, 2048);
}

// Round 9
// 245.507 us; speedup vs baseline: 1.0470x; 1.0470x over previous
//
#include <hip/hip_runtime.h>
#include <hip/hip_bf16.h>
#include <math.h>

typedef __bf16 bf16;
typedef __attribute__((ext_vector_type(8))) __bf16 bf16x8;
typedef __attribute__((ext_vector_type(4))) __bf16 bf16x4;
typedef __attribute__((ext_vector_type(4))) float f32x4;

#define MFMA16(a,b,c) __builtin_amdgcn_mfma_f32_16x16x32_bf16(a,b,c,0,0,0)

// Problem constants
#define BATCH 2
#define SEQ   2048
#define DMODEL 768
#define NH    12
#define NKV   4
#define NREP  3
#define HD    64
#define FFDIM 2048
#define ROWS  (BATCH*SEQ)   // 4096

#define QSCALE 0.18033688011112042f
#define LOG2E  1.4426950408889634f

// Partial-drain barrier: wait until <=N of THIS wave's vmem ops outstanding,
// then barrier.  After all waves pass, every wave's covered loads are in LDS.
#define WB(N) asm volatile("s_waitcnt vmcnt(" #N ")\n\ts_barrier" ::: "memory")
#define BAR() asm volatile("s_barrier" ::: "memory")

__device__ __forceinline__ void gl2lds16(const bf16* g, bf16* l) {
  __builtin_amdgcn_global_load_lds(
      (const __attribute__((address_space(1))) void*)g,
      (__attribute__((address_space(3))) void*)l, 16, 0, 0);
}

// ---------------- fused fp32 -> bf16 convert (7 segs) + RoPE table (seg 7) ----------------
// Segs 4/5 (Wgate/Wup) are INTERLEAVED into one W' [4096][768]:
//   W'[64p + j]      = Wgate[32p + j]
//   W'[64p + 32 + j] = Wup  [32p + j]
struct Cvt7 { const float* s[7]; bf16* d[7]; int n[7]; float* tab; };
__global__ __launch_bounds__(256) void cvt_all_kernel(Cvt7 c) {
  int seg = blockIdx.y;
  if (seg == 7) {
    int id = blockIdx.x * 256 + threadIdx.x;    // 65536 = 32 j * 2048 s
    int j = id >> 11, s = id & 2047;
    float inv = expf(-(float)j * (9.210340371976184f / 32.0f));
    float ang = (float)s * inv;
    c.tab[id] = cosf(ang);
    c.tab[65536 + id] = sinf(ang);
    return;
  }
  const float* __restrict__ src = c.s[seg];
  bf16* __restrict__ dst = c.d[seg];
  int n = c.n[seg];
  int stride = gridDim.x * 256;
  if (seg == 4 || seg == 5) {
    int up = (seg == 5) ? 32 : 0;
    for (int i = blockIdx.x * 256 + threadIdx.x; i < n; i += stride) {
      int rg = i / 768, cc = i - rg * 768;
      int drow = ((rg >> 5) << 6) + (rg & 31) + up;
      dst[(size_t)drow * 768 + cc] = (bf16)src[i];
    }
    return;
  }
  for (int i = blockIdx.x * 256 + threadIdx.x; i < n; i += stride)
    dst[i] = (bf16)src[i];
}

// ---------------- RMSNorm (vectorized f32x4, 192 threads) ----------------
__global__ __launch_bounds__(192) void rmsnorm_kernel(const float* __restrict__ x,
    const float* __restrict__ g, bf16* __restrict__ out) {
  int row = blockIdx.x;
  const float* xr = x + (size_t)row * DMODEL;
  int t = threadIdx.x;
  f32x4 v = *(const f32x4*)(xr + t * 4);
  float ss = v[0] * v[0] + v[1] * v[1] + v[2] * v[2] + v[3] * v[3];
  #pragma unroll
  for (int off = 32; off; off >>= 1) ss += __shfl_xor(ss, off, 64);
  __shared__ float red[3];
  if ((t & 63) == 0) red[t >> 6] = ss;
  __syncthreads();
  float total = red[0] + red[1] + red[2];
  float norm = sqrtf(total) * 0.03608439182435161f;  // 768^-0.5
  float sc = 1.0f / (norm + 1e-6f);
  f32x4 gv = *(const f32x4*)(g + t * 4);
  bf16x4 o;
  #pragma unroll
  for (int i = 0; i < 4; ++i) o[i] = (bf16)(gv[i] * v[i] * sc);
  *(bf16x4*)(out + (size_t)row * DMODEL + t * 4) = o;
}

// ---------------- Output GEMM 64x64, in-block split-K=2, 8 waves ----------------
__global__ __launch_bounds__(512, 6) void gemm_out_kernel(const bf16* __restrict__ A,
    const bf16* __restrict__ B, float* __restrict__ C, const float* __restrict__ R,
    int N, int K) {
  __shared__ __align__(16) bf16 At[2][3][64 * 32];   // 24KB
  __shared__ __align__(16) bf16 Bt[2][3][64 * 32];   // 24KB
  int t = threadIdx.x;
  int g = t >> 8;                    // K-group (0: lower half, 1: upper half)
  int tt = t & 255;                  // thread-in-group
  int lane = t & 63;
  int w = (t >> 6) & 3;              // wave-in-group
  int l15 = lane & 15, lq = lane >> 4;
  int wrow = (w >> 1) * 32, wcol = (w & 1) * 32;

  // XCD-chunked remap: 768 wgs = 8 XCDs x 96; same-A row-strips go to one XCD.
  int flat = blockIdx.y * 12 + blockIdx.x;
  int f2 = (flat & 7) * 96 + (flat >> 3);
  int col0 = (f2 % 12) * 64, row0 = (f2 / 12) * 64;

  const int KH = K >> 1;
  const int NS = KH / 32;            // 12 (Wo, K=768) or 32 (Wdown, K=2048)
  const bf16* Ag = A + (size_t)(row0 + (tt >> 2)) * K + g * KH + (tt & 3) * 8;
  const bf16* Bg = B + (size_t)(col0 + (tt >> 2)) * K + g * KH + (tt & 3) * 8;

  #pragma unroll
  for (int s = 0; s < 2; ++s) {
    gl2lds16(Ag + s * 32, At[g][s] + tt * 8);
    gl2lds16(Bg + s * 32, Bt[g][s] + tt * 8);
  }

  f32x4 zero = {0.f, 0.f, 0.f, 0.f};
  f32x4 acc[2][2];
  #pragma unroll
  for (int m = 0; m < 2; ++m)
    #pragma unroll
    for (int n = 0; n < 2; ++n) acc[m][n] = zero;

  #define OG_COMPUTE(slot) do {                                              \
    const bf16* at = At[g][slot]; const bf16* bt = Bt[g][slot];              \
    bf16x8 af[2], bb[2];                                                     \
    _Pragma("unroll")                                                        \
    for (int m = 0; m < 2; ++m)                                              \
      af[m] = *(const bf16x8*)(at + (wrow + m * 16 + l15) * 32 + lq * 8);    \
    _Pragma("unroll")                                                        \
    for (int n = 0; n < 2; ++n)                                              \
      bb[n] = *(const bf16x8*)(bt + (wcol + n * 16 + l15) * 32 + lq * 8);    \
    _Pragma("unroll")                                                        \
    for (int m = 0; m < 2; ++m)                                              \
      _Pragma("unroll")                                                      \
      for (int n = 0; n < 2; ++n)                                            \
        acc[m][n] = MFMA16(af[m], bb[n], acc[m][n]);                         \
  } while (0)

  int slot = 0;
  for (int k = 0; k < NS - 1; ++k) {
    WB(2);                        // stage k resident; stage k+1 may be in flight
    if (k + 2 < NS) {
      int ks = (k + 2) * 32;
      int ws = slot + 2; if (ws >= 3) ws -= 3;   // (k+2)%3 == (k-1)%3
      gl2lds16(Ag + ks, At[g][ws] + tt * 8);
      gl2lds16(Bg + ks, Bt[g][ws] + tt * 8);
    }
    OG_COMPUTE(slot);
    slot = (slot == 2) ? 0 : slot + 1;
  }
  WB(0);
  OG_COMPUTE(slot);
  #undef OG_COMPUTE

  // ---- combine K-halves through LDS overlay (16KB over At), then store ----
  __syncthreads();                  // all LDS reads for compute complete
  float* Cl = (float*)&At[0][0][0];
  if (g == 1) {
    #pragma unroll
    for (int m = 0; m < 2; ++m)
      #pragma unroll
      for (int n = 0; n < 2; ++n)
        #pragma unroll
        for (int r = 0; r < 4; ++r)
          Cl[(wrow + m * 16 + lq * 4 + r) * 64 + wcol + n * 16 + l15] = acc[m][n][r];
  }
  __syncthreads();
  if (g == 0) {
    #pragma unroll
    for (int m = 0; m < 2; ++m)
      #pragma unroll
      for (int n = 0; n < 2; ++n)
        #pragma unroll
        for (int r = 0; r < 4; ++r) {
          int row = wrow + m * 16 + lq * 4 + r;
          int col = wcol + n * 16 + l15;
          size_t idx = (size_t)(row0 + row) * N + col0 + col;
          C[idx] = acc[m][n][r] + Cl[row * 64 + col] + R[idx];
        }
  }
}

// ---------------- QKV GEMM + fused RoPE epilogue: ring-4, single barrier ----------------
__global__ __launch_bounds__(256) void gemm_qkv_kernel(const bf16* __restrict__ A,
    const bf16* __restrict__ Wcat, const float* __restrict__ tab,
    bf16* __restrict__ Qh, bf16* __restrict__ Kh, bf16* __restrict__ Vt) {
  __shared__ __align__(16) bf16 At[4][64 * 32];
  __shared__ __align__(16) bf16 Bt[4][128 * 32];
  const int K = DMODEL;
  int t = threadIdx.x, lane = t & 63, wave = t >> 6;
  int l15 = lane & 15, lq = lane >> 4;
  int wrow = (wave >> 1) * 32, wcol = (wave & 1) * 64;
  int row0 = blockIdx.y * 64, col0 = blockIdx.x * 128;
  const bf16* Ag  = A + (size_t)(row0 + (t >> 2)) * K + (t & 3) * 8;
  const bf16* Bg0 = Wcat + (size_t)(col0 + (t >> 2)) * K + (t & 3) * 8;
  const bf16* Bg1 = Bg0 + (size_t)64 * K;
  const int NS = K / 32;   // 24

  #pragma unroll
  for (int s = 0; s < 3; ++s) {
    int ks = s * 32;
    gl2lds16(Ag + ks,  At[s] + t * 8);
    gl2lds16(Bg0 + ks, Bt[s] + t * 8);
    gl2lds16(Bg1 + ks, Bt[s] + 2048 + t * 8);
  }

  f32x4 zero = {0.f, 0.f, 0.f, 0.f};
  f32x4 acc[2][4];
  #pragma unroll
  for (int m = 0; m < 2; ++m)
    #pragma unroll
    for (int n = 0; n < 4; ++n) acc[m][n] = zero;

  #define QK_COMPUTE(slot) do {                                              \
    const bf16* at = At[slot]; const bf16* bt = Bt[slot];                    \
    bf16x8 af[2], bfr[4];                                                    \
    _Pragma("unroll")                                                        \
    for (int m = 0; m < 2; ++m)                                              \
      af[m] = *(const bf16x8*)(at + (wrow + m * 16 + l15) * 32 + lq * 8);    \
    _Pragma("unroll")                                                        \
    for (int n = 0; n < 4; ++n)                                              \
      bfr[n] = *(const bf16x8*)(bt + (wcol + n * 16 + l15) * 32 + lq * 8);   \
    _Pragma("unroll")                                                        \
    for (int m = 0; m < 2; ++m)                                              \
      _Pragma("unroll")                                                      \
      for (int n = 0; n < 4; ++n)                                            \
        acc[m][n] = MFMA16(af[m], bfr[n], acc[m][n]);                        \
  } while (0)

  for (int k = 0; k < NS - 2; ++k) {
    WB(6);
    if (k + 3 < NS) {
      int ks = (k + 3) * 32;
      int ws = (k + 3) & 3;
      gl2lds16(Ag + ks,  At[ws] + t * 8);
      gl2lds16(Bg0 + ks, Bt[ws] + t * 8);
      gl2lds16(Bg1 + ks, Bt[ws] + 2048 + t * 8);
    }
    QK_COMPUTE(k & 3);
  }
  WB(3);
  QK_COMPUTE((NS - 2) & 3);
  WB(0);
  QK_COMPUTE((NS - 1) & 3);
  #undef QK_COMPUTE

  // ---- epilogue: RoPE (Q,K) / transpose-store (V) ----
  int b = row0 >> 11;
  int s0 = (row0 & 2047) + wrow + lq * 4;
  int colw = col0 + wcol;
  if (colw < 768) {
    int h = colw >> 6;
    f32x4 cv[2][2], sv[2][2];
    #pragma unroll
    for (int m = 0; m < 2; ++m)
      #pragma unroll
      for (int jh = 0; jh < 2; ++jh) {
        const float* cp = tab + (jh * 16 + l15) * 2048 + s0 + m * 16;
        cv[m][jh] = *(const f32x4*)cp;
        sv[m][jh] = *(const f32x4*)(cp + 65536);
      }
    #pragma unroll
    for (int m = 0; m < 2; ++m)
      #pragma unroll
      for (int n = 0; n < 4; ++n) {
        float sgn = (n < 2) ? -1.f : 1.f;
        #pragma unroll
        for (int r = 0; r < 4; ++r) {
          float c = cv[m][n & 1][r], si = sv[m][n & 1][r];
          float rp = (acc[m][n][r] * c + sgn * acc[m][n ^ 2][r] * si) * QSCALE;
          Qh[((size_t)(b * NH + h) * SEQ + s0 + m * 16 + r) * 64 + n * 16 + l15] = (bf16)rp;
        }
      }
  } else if (colw < 1024) {
    int kh = (colw - 768) >> 6;
    f32x4 cv[2][2], sv[2][2];
    #pragma unroll
    for (int m = 0; m < 2; ++m)
      #pragma unroll
      for (int jh = 0; jh < 2; ++jh) {
        const float* cp = tab + (jh * 16 + l15) * 2048 + s0 + m * 16;
        cv[m][jh] = *(const f32x4*)cp;
        sv[m][jh] = *(const f32x4*)(cp + 65536);
      }
    #pragma unroll
    for (int m = 0; m < 2; ++m)
      #pragma unroll
      for (int n = 0; n < 4; ++n) {
        float sgn = (n < 2) ? -1.f : 1.f;
        #pragma unroll
        for (int r = 0; r < 4; ++r) {
          float c = cv[m][n & 1][r], si = sv[m][n & 1][r];
          float rp = acc[m][n][r] * c + sgn * acc[m][n ^ 2][r] * si;
          Kh[((size_t)(b * NKV + kh) * SEQ + s0 + m * 16 + r) * 64 + n * 16 + l15] = (bf16)rp;
        }
      }
  } else {
    int vh = (colw - 1024) >> 6;
    #pragma unroll
    for (int m = 0; m < 2; ++m)
      #pragma unroll
      for (int n = 0; n < 4; ++n) {
        bf16x4 pv;
        #pragma unroll
        for (int r = 0; r < 4; ++r) pv[r] = (bf16)acc[m][n][r];
        *(bf16x4*)(Vt + ((size_t)(b * NKV + vh) * 64 + n * 16 + l15) * SEQ + s0 + m * 16) = pv;
      }
  }
}

// ---------------- Gate/up fused GEMM + silu: 256x256 8-phase, fragment-major LDS ----------------
// (reverted to the round-6 best-measured configuration)
__global__ __launch_bounds__(512, 2) void gemm_gu_kernel(const bf16* __restrict__ A,
    const bf16* __restrict__ W, bf16* __restrict__ H) {
  __shared__ __align__(16) bf16 Als[2 * 2 * 128 * 64];   // 64KB
  __shared__ __align__(16) bf16 Bls[2 * 2 * 128 * 64];   // 64KB
  const int NT = 12;                 // 768 / 64
  int t = threadIdx.x, lane = t & 63, wave = t >> 6;
  int l15 = lane & 15, lq = lane >> 4;
  int lfrag = l15 * 32 + lq * 8;     // lane's chunk offset (bf16) within (m,kk) group
  int wm = wave >> 2, wn = wave & 3;

  // XCD-chunked bijective remap: 256 blocks = 8 XCDs x 32.
  int flat = blockIdx.y * 16 + blockIdx.x;
  int f2 = (flat & 7) * 32 + (flat >> 3);
  int colb = f2 & 15, rowb = f2 >> 4;
  int row0 = rowb * 256, col0w = colb * 256;

  // Fragment-major stage: thread t loads chunks t and t+512 of half h, tile j.
  #define STAGE(G, orow, L, j, h) do {                                       \
    bf16* lb = (L) + ((j) & 1) * 16384 + (h) * 8192 + t * 8;                 \
    const bf16* gb = (G) + (size_t)((orow) + (h) * 128 + ((t >> 7) << 4)     \
                   + ((t >> 2) & 15)) * 768 + (j) * 64                       \
                   + ((t >> 6) & 1) * 32 + (t & 3) * 8;                      \
    gl2lds16(gb, lb);                                                        \
    gl2lds16(gb + (size_t)64 * 768, lb + 4096);                              \
  } while (0)

  // Prologue in steady-state issue order: B(0), A(0), B(1)  (6 stages, 12 loads)
  STAGE(W, col0w, Bls, 0, 0);  STAGE(W, col0w, Bls, 0, 1);
  STAGE(A, row0,  Als, 0, 0);  STAGE(A, row0,  Als, 0, 1);
  STAGE(W, col0w, Bls, 1, 0);  STAGE(W, col0w, Bls, 1, 1);

  f32x4 zero = {0.f, 0.f, 0.f, 0.f};
  f32x4 acc[8][4];
  #pragma unroll
  for (int m = 0; m < 8; ++m)
    #pragma unroll
    for (int n = 0; n < 4; ++n) acc[m][n] = zero;

  WB(4);                             // tile-0 halves landed; B(1) in flight

  for (int j = 0; j < NT; ++j) {
    const bf16* aB = Als + (j & 1) * 16384 + wm * 8192 + lfrag;
    const bf16* bB = Bls + (j & 1) * 16384 + (wn >> 1) * 8192 + (wn & 1) * 4096 + lfrag;
    bf16x8 afr[4][2], bfr[4][2];

    // ---- phase 0: read A m0-3 + B n0-1 (12 ds_reads); stage A0(j+1) ----
    #pragma unroll
    for (int m = 0; m < 4; ++m)
      #pragma unroll
      for (int kk = 0; kk < 2; ++kk)
        afr[m][kk] = *(const bf16x8*)(aB + m * 1024 + kk * 512);
    #pragma unroll
    for (int n = 0; n < 2; ++n)
      #pragma unroll
      for (int kk = 0; kk < 2; ++kk)
        bfr[n][kk] = *(const bf16x8*)(bB + n * 1024 + kk * 512);
    if (j + 1 < NT) STAGE(A, row0, Als, j + 1, 0);
    BAR();
    __builtin_amdgcn_s_setprio(1);
    #pragma unroll
    for (int m = 0; m < 4; ++m)
      #pragma unroll
      for (int n = 0; n < 2; ++n) {
        acc[m][n] = MFMA16(afr[m][0], bfr[n][0], acc[m][n]);
        acc[m][n] = MFMA16(afr[m][1], bfr[n][1], acc[m][n]);
      }
    __builtin_amdgcn_s_setprio(0);
    BAR();

    // ---- phase 1: read B n2-3 (4 ds_reads); stage A1(j+1) ----
    #pragma unroll
    for (int n = 2; n < 4; ++n)
      #pragma unroll
      for (int kk = 0; kk < 2; ++kk)
        bfr[n][kk] = *(const bf16x8*)(bB + n * 1024 + kk * 512);
    if (j + 1 < NT) STAGE(A, row0, Als, j + 1, 1);
    BAR();
    __builtin_amdgcn_s_setprio(1);
    #pragma unroll
    for (int m = 0; m < 4; ++m)
      #pragma unroll
      for (int n = 2; n < 4; ++n) {
        acc[m][n] = MFMA16(afr[m][0], bfr[n][0], acc[m][n]);
        acc[m][n] = MFMA16(afr[m][1], bfr[n][1], acc[m][n]);
      }
    __builtin_amdgcn_s_setprio(0);
    BAR();

    // ---- phase 2: read A m4-7 (8 ds_reads); stage B0(j+2) ----
    #pragma unroll
    for (int m = 0; m < 4; ++m)
      #pragma unroll
      for (int kk = 0; kk < 2; ++kk)
        afr[m][kk] = *(const bf16x8*)(aB + (m + 4) * 1024 + kk * 512);
    if (j + 2 < NT) STAGE(W, col0w, Bls, j + 2, 0);
    BAR();
    __builtin_amdgcn_s_setprio(1);
    #pragma unroll
    for (int m = 0; m < 4; ++m)
      #pragma unroll
      for (int n = 0; n < 2; ++n) {
        acc[m + 4][n] = MFMA16(afr[m][0], bfr[n][0], acc[m + 4][n]);
        acc[m + 4][n] = MFMA16(afr[m][1], bfr[n][1], acc[m + 4][n]);
      }
    __builtin_amdgcn_s_setprio(0);
    BAR();

    // ---- phase 3: stage B1(j+2); MFMA m4-7 x n2-3 ----
    if (j + 2 < NT) STAGE(W, col0w, Bls, j + 2, 1);
    BAR();
    __builtin_amdgcn_s_setprio(1);
    #pragma unroll
    for (int m = 0; m < 4; ++m)
      #pragma unroll
      for (int n = 2; n < 4; ++n) {
        acc[m + 4][n] = MFMA16(afr[m][0], bfr[n][0], acc[m + 4][n]);
        acc[m + 4][n] = MFMA16(afr[m][1], bfr[n][1], acc[m + 4][n]);
      }
    __builtin_amdgcn_s_setprio(0);
    // ---- tile boundary: counted vmcnt + barrier ----
    if (j < NT - 2)       WB(4);     // B(j+2) stages (4 loads) stay in flight
    else if (j == NT - 2) WB(0);     // drain A(NT-1); nothing newer exists
  }
  #undef STAGE

  // ---- epilogue: silu(gate)*up, wave-local pairing acc[m][n] / acc[m][n+2] ----
  int hc0 = colb * 128 + wn * 32;
  #pragma unroll
  for (int m = 0; m < 8; ++m)
    #pragma unroll
    for (int n = 0; n < 2; ++n)
      #pragma unroll
      for (int r = 0; r < 4; ++r) {
        int row = row0 + wm * 128 + m * 16 + lq * 4 + r;
        int col = hc0 + n * 16 + l15;
        float g = acc[m][n][r], u = acc[m][n + 2][r];
        float sg = g / (1.f + __builtin_amdgcn_exp2f(-g * LOG2E));
        H[(size_t)row * FFDIM + col] = (bf16)(sg * u);
      }
}

// ---------------- Flash attention: 8 waves / 128 q-rows, fragment-major K/V ----------------
// 384 blocks (16 q-tiles x 24 bh), 512 threads.  One K/V stage serves 8 waves
// (halves K/V HBM+staging traffic vs the 4-wave version); LDS 52KB -> 3
// blocks/CU = 24 waves/CU (2x occupancy).  K/V tiles are 64x64 fragment-major:
// chunk c holds (row (c>>7)*16+((c>>2)&15), col ((c>>6)&1)*32+(c&3)*8); the
// per-MFMA read kl + (c*2+kk)*512 + l15*32+lq*8 is 64 consecutive 16B chunks.
// 512 threads stage a full 64x64 tile with ONE gl2lds each (2/thread/step).
__global__ __launch_bounds__(512) void attn_kernel(const bf16* __restrict__ Qh,
    const bf16* __restrict__ Kh, const bf16* __restrict__ Vt, bf16* __restrict__ out) {
  __shared__ __align__(16) bf16 Kl[2][64 * 64];   // 16KB
  __shared__ __align__(16) bf16 Vl[2][64 * 64];   // 16KB
  __shared__ __align__(16) bf16 P[8][16 * 80];    // 20KB

  int idx = blockIdx.x;
  int qt = 15 - (idx / 24);                      // LPT: heaviest first
  int bh = idx % 24;
  int q0blk = qt * 128;
  int b = bh / NH, h = bh % NH;
  int kvh = h / NREP;
  int t = threadIdx.x;
  int lane = t & 63, wave = t >> 6;              // wave 0..7
  int l15 = lane & 15, lq = lane >> 4;
  int qw = q0blk + wave * 16;
  const bf16* Qb = Qh + (size_t)(b * NH + h) * SEQ * 64;
  const bf16* Kb = Kh + (size_t)(b * NKV + kvh) * SEQ * 64;
  const bf16* Vb = Vt + (size_t)(b * NKV + kvh) * 64 * SEQ;

  bf16x8 bq0 = *(const bf16x8*)(Qb + (size_t)(qw + l15) * 64 + lq * 8);
  bf16x8 bq1 = *(const bf16x8*)(Qb + (size_t)(qw + l15) * 64 + 32 + lq * 8);

  // fragment-major staging source for thread t (covers chunk t of a 64x64 tile)
  int srow = ((t >> 7) << 4) + ((t >> 2) & 15);  // 0..63
  int scol = ((t >> 6) & 1) * 32 + (t & 3) * 8;  // 0..63
  const bf16* Kg = Kb + (size_t)srow * 64 + scol;   // K: row=key, col=d
  const bf16* Vg = Vb + (size_t)srow * SEQ + scol;  // V: row=d,  col=key
  bf16* Pw = P[wave];
  int Pwq = l15 * 80, lq8 = lq * 8, lq4 = lq * 4;
  int lfrag = l15 * 32 + lq8;                    // fragment-major read offset
  const int NS = 2 * (qt + 1);                   // 64-key steps (2..32)

  #pragma unroll
  for (int s = 0; s < 2; ++s) {
    int ks = s * 64;                             // NS >= 2 always
    gl2lds16(Kg + (size_t)ks * 64, Kl[s] + t * 8);
    gl2lds16(Vg + ks,              Vl[s] + t * 8);
  }

  f32x4 zero = {0.f, 0.f, 0.f, 0.f};
  f32x4 o[4];
  o[0] = zero; o[1] = zero; o[2] = zero; o[3] = zero;
  float l_r = 0.f;

  #define ATTN_STEP(kk, slot) do {                                           \
    int k0 = (kk) * 64;                                                      \
    const bf16* kl = Kl[slot]; const bf16* vl = Vl[slot];                    \
    f32x4 s[4];                                                              \
    _Pragma("unroll")                                                        \
    for (int c = 0; c < 4; ++c) {                                            \
      bf16x8 ak0 = *(const bf16x8*)(kl + (c * 2 + 0) * 512 + lfrag);         \
      bf16x8 ak1 = *(const bf16x8*)(kl + (c * 2 + 1) * 512 + lfrag);         \
      s[c] = zero;                                                           \
      s[c] = MFMA16(ak0, bq0, s[c]);                                         \
      s[c] = MFMA16(ak1, bq1, s[c]);                                         \
    }                                                                        \
    if (k0 + 63 > qw) {                                                      \
      int qmk = qw + l15 - k0 - lq4;                                         \
      _Pragma("unroll")                                                      \
      for (int c = 0; c < 4; ++c)                                            \
        _Pragma("unroll")                                                    \
        for (int r = 0; r < 4; ++r)                                          \
          if (c * 16 + r > qmk) s[c][r] = -INFINITY;                         \
    }                                                                        \
    _Pragma("unroll")                                                        \
    for (int c = 0; c < 4; ++c) {                                            \
      bf16x4 pe;                                                             \
      _Pragma("unroll")                                                      \
      for (int r = 0; r < 4; ++r) {                                          \
        float e = __builtin_amdgcn_exp2f(s[c][r]);                           \
        l_r += e;                                                            \
        pe[r] = (bf16)e;                                                     \
      }                                                                      \
      *(bf16x4*)(Pw + Pwq + c * 16 + lq4) = pe;                              \
    }                                                                        \
    bf16x8 bp0 = *(const bf16x8*)(Pw + Pwq + lq8);                           \
    bf16x8 bp1 = *(const bf16x8*)(Pw + Pwq + 32 + lq8);                      \
    _Pragma("unroll")                                                        \
    for (int n = 0; n < 4; ++n) {                                            \
      bf16x8 av0 = *(const bf16x8*)(vl + (n * 2 + 0) * 512 + lfrag);         \
      bf16x8 av1 = *(const bf16x8*)(vl + (n * 2 + 1) * 512 + lfrag);         \
      o[n] = MFMA16(av0, bp0, o[n]);                                         \
      o[n] = MFMA16(av1, bp1, o[n]);                                         \
    }                                                                        \
  } while (0)

  for (int k = 0; k < NS - 1; ++k) {
    WB(2);                        // stage k resident (stage k+1 = 2 loads in flight)
    ATTN_STEP(k, k & 1);
    BAR();
    if (k <= NS - 3) {
      int ks = (k + 2) * 64;
      gl2lds16(Kg + (size_t)ks * 64, Kl[k & 1] + t * 8);
      gl2lds16(Vg + ks,              Vl[k & 1] + t * 8);
    }
  }
  {
    WB(0);
    ATTN_STEP(NS - 1, (NS - 1) & 1);
  }
  #undef ATTN_STEP

  float lt = l_r;
  lt += __shfl_xor(lt, 16, 64);
  lt += __shfl_xor(lt, 32, 64);
  float inv = 1.f / lt;
  int q = qw + l15;
  bf16* orow = out + (size_t)(b * SEQ + q) * DMODEL + h * 64;
  #pragma unroll
  for (int n = 0; n < 4; ++n) {
    bf16x4 po;
    #pragma unroll
    for (int r = 0; r < 4; ++r) po[r] = (bf16)(o[n][r] * inv);
    *(bf16x4*)(orow + n * 16 + lq4) = po;
  }
}

extern "C" void kernel_launch(void* const* d_in, const int* in_sizes, int n_in,
                              void* d_out, int out_size, void* d_ws, size_t ws_size,
                              hipStream_t stream) {
  const float* x     = (const float*)d_in[0];
  const float* Wq    = (const float*)d_in[1];
  const float* Wk    = (const float*)d_in[2];
  const float* Wv    = (const float*)d_in[3];
  const float* Wo    = (const float*)d_in[4];
  const float* Wgate = (const float*)d_in[5];
  const float* Wup   = (const float*)d_in[6];
  const float* Wdown = (const float*)d_in[7];
  const float* g1    = (const float*)d_in[8];
  const float* g2    = (const float*)d_in[9];
  float* out = (float*)d_out;

  char* ws = (char*)d_ws;
  size_t off = 0;
  auto alloc = [&](size_t bytes) { size_t o = off; off += (bytes + 255) & ~(size_t)255; return o; };
  size_t o_tab  = alloc((size_t)2 * 32 * 2048 * 4);          // 512KB cos/sin
  size_t o_x1   = alloc((size_t)4096 * 768 * 4);
  size_t o_xn   = alloc((size_t)4096 * 768 * 2);
  size_t o_Qh   = alloc((size_t)2 * 12 * 2048 * 64 * 2);
  size_t o_Kh   = alloc((size_t)2 * 4 * 2048 * 64 * 2);
  size_t o_Vt   = alloc((size_t)2 * 4 * 64 * 2048 * 2);
  size_t o_ao   = alloc((size_t)4096 * 768 * 2);
  size_t o_H    = alloc((size_t)4096 * 2048 * 2);
  size_t o_Wcat = alloc((size_t)1280 * 768 * 2);
  size_t o_Wo   = alloc((size_t)768 * 768 * 2);
  size_t o_Wgu  = alloc((size_t)4096 * 768 * 2);
  size_t o_Wdn  = alloc((size_t)768 * 2048 * 2);
  if (ws_size < off) return;

  float* tab  = (float*)(ws + o_tab);
  float* fx1  = (float*)(ws + o_x1);
  bf16* bxn   = (bf16*)(ws + o_xn);
  bf16* bQh   = (bf16*)(ws + o_Qh);
  bf16* bKh   = (bf16*)(ws + o_Kh);
  bf16* bVt   = (bf16*)(ws + o_Vt);
  bf16* bao   = (bf16*)(ws + o_ao);
  bf16* bH    = (bf16*)(ws + o_H);
  bf16* bWcat = (bf16*)(ws + o_Wcat);
  bf16* bWo   = (bf16*)(ws + o_Wo);
  bf16* bWgu  = (bf16*)(ws + o_Wgu);
  bf16* bWdn  = (bf16*)(ws + o_Wdn);

  Cvt7 c;
  c.s[0] = Wq;    c.d[0] = bWcat;              c.n[0] = 768 * 768;
  c.s[1] = Wk;    c.d[1] = bWcat + 768 * 768;  c.n[1] = 256 * 768;
  c.s[2] = Wv;    c.d[2] = bWcat + 1024 * 768; c.n[2] = 256 * 768;
  c.s[3] = Wo;    c.d[3] = bWo;                c.n[3] = 768 * 768;
  c.s[4] = Wgate; c.d[4] = bWgu;               c.n[4] = 2048 * 768;   // interleaved
  c.s[5] = Wup;   c.d[5] = bWgu;               c.n[5] = 2048 * 768;   // interleaved
  c.s[6] = Wdown; c.d[6] = bWdn;               c.n[6] = 768 * 2048;
  c.tab = tab;
  cvt_all_kernel<<<dim3(256, 8), 256, 0, stream>>>(c);

  // Attention sublayer
  rmsnorm_kernel<<<4096, 192, 0, stream>>>(x, g1, bxn);
  gemm_qkv_kernel<<<dim3(10, 64), 256, 0, stream>>>(bxn, bWcat, tab, bQh, bKh, bVt);
  attn_kernel<<<dim3(384), 512, 0, stream>>>(bQh, bKh, bVt, bao);
  gemm_out_kernel<<<dim3(12, 64), 512, 0, stream>>>(bao, bWo, fx1, x, 768, 768);

  // FFN sublayer
  rmsnorm_kernel<<<4096, 192, 0, stream>>>(fx1, g2, bxn);
  gemm_gu_kernel<<<dim3(16, 16), 512, 0, stream>>>(bxn, bWgu, bH);
  gemm_out_kernel<<<dim3(12, 64), 512, 0, stream>>>(bH, bWdn, out, fx1, 768, 2048);
}

// Round 10
// 238.477 us; speedup vs baseline: 1.0779x; 1.0295x over previous
//
#include <hip/hip_runtime.h>
#include <hip/hip_bf16.h>
#include <math.h>

typedef __bf16 bf16;
typedef __attribute__((ext_vector_type(8))) __bf16 bf16x8;
typedef __attribute__((ext_vector_type(4))) __bf16 bf16x4;
typedef __attribute__((ext_vector_type(4))) float f32x4;

#define MFMA16(a,b,c) __builtin_amdgcn_mfma_f32_16x16x32_bf16(a,b,c,0,0,0)

// Problem constants
#define BATCH 2
#define SEQ   2048
#define DMODEL 768
#define NH    12
#define NKV   4
#define NREP  3
#define HD    64
#define FFDIM 2048
#define ROWS  (BATCH*SEQ)   // 4096

#define QSCALE 0.18033688011112042f
#define LOG2E  1.4426950408889634f

// Partial-drain barrier: wait until <=N of THIS wave's vmem ops outstanding,
// then barrier.  After all waves pass, every wave's covered loads are in LDS.
#define WB(N) asm volatile("s_waitcnt vmcnt(" #N ")\n\ts_barrier" ::: "memory")
#define BAR() asm volatile("s_barrier" ::: "memory")

__device__ __forceinline__ void gl2lds16(const bf16* g, bf16* l) {
  __builtin_amdgcn_global_load_lds(
      (const __attribute__((address_space(1))) void*)g,
      (__attribute__((address_space(3))) void*)l, 16, 0, 0);
}

// ---------------- fused fp32 -> bf16 convert (7 segs) + RoPE table (seg 7) ----------------
// Segs 4/5 (Wgate/Wup) are INTERLEAVED into one W' [4096][768]:
//   W'[64p + j]      = Wgate[32p + j]
//   W'[64p + 32 + j] = Wup  [32p + j]
struct Cvt7 { const float* s[7]; bf16* d[7]; int n[7]; float* tab; };
__global__ __launch_bounds__(256) void cvt_all_kernel(Cvt7 c) {
  int seg = blockIdx.y;
  if (seg == 7) {
    int id = blockIdx.x * 256 + threadIdx.x;    // 65536 = 32 j * 2048 s
    int j = id >> 11, s = id & 2047;
    float inv = expf(-(float)j * (9.210340371976184f / 32.0f));
    float ang = (float)s * inv;
    c.tab[id] = cosf(ang);
    c.tab[65536 + id] = sinf(ang);
    return;
  }
  const float* __restrict__ src = c.s[seg];
  bf16* __restrict__ dst = c.d[seg];
  int n = c.n[seg];
  int stride = gridDim.x * 256;
  if (seg == 4 || seg == 5) {
    int up = (seg == 5) ? 32 : 0;
    for (int i = blockIdx.x * 256 + threadIdx.x; i < n; i += stride) {
      int rg = i / 768, cc = i - rg * 768;
      int drow = ((rg >> 5) << 6) + (rg & 31) + up;
      dst[(size_t)drow * 768 + cc] = (bf16)src[i];
    }
    return;
  }
  for (int i = blockIdx.x * 256 + threadIdx.x; i < n; i += stride)
    dst[i] = (bf16)src[i];
}

// ---------------- RMSNorm (vectorized f32x4, 192 threads) ----------------
__global__ __launch_bounds__(192) void rmsnorm_kernel(const float* __restrict__ x,
    const float* __restrict__ g, bf16* __restrict__ out) {
  int row = blockIdx.x;
  const float* xr = x + (size_t)row * DMODEL;
  int t = threadIdx.x;
  f32x4 v = *(const f32x4*)(xr + t * 4);
  float ss = v[0] * v[0] + v[1] * v[1] + v[2] * v[2] + v[3] * v[3];
  #pragma unroll
  for (int off = 32; off; off >>= 1) ss += __shfl_xor(ss, off, 64);
  __shared__ float red[3];
  if ((t & 63) == 0) red[t >> 6] = ss;
  __syncthreads();
  float total = red[0] + red[1] + red[2];
  float norm = sqrtf(total) * 0.03608439182435161f;  // 768^-0.5
  float sc = 1.0f / (norm + 1e-6f);
  f32x4 gv = *(const f32x4*)(g + t * 4);
  bf16x4 o;
  #pragma unroll
  for (int i = 0; i < 4; ++i) o[i] = (bf16)(gv[i] * v[i] * sc);
  *(bf16x4*)(out + (size_t)row * DMODEL + t * 4) = o;
}

// ---------------- Output GEMM 64x64, in-block split-K=2, 8 waves ----------------
__global__ __launch_bounds__(512, 6) void gemm_out_kernel(const bf16* __restrict__ A,
    const bf16* __restrict__ B, float* __restrict__ C, const float* __restrict__ R,
    int N, int K) {
  __shared__ __align__(16) bf16 At[2][3][64 * 32];   // 24KB
  __shared__ __align__(16) bf16 Bt[2][3][64 * 32];   // 24KB
  int t = threadIdx.x;
  int g = t >> 8;                    // K-group (0: lower half, 1: upper half)
  int tt = t & 255;                  // thread-in-group
  int lane = t & 63;
  int w = (t >> 6) & 3;              // wave-in-group
  int l15 = lane & 15, lq = lane >> 4;
  int wrow = (w >> 1) * 32, wcol = (w & 1) * 32;

  // XCD-chunked remap: 768 wgs = 8 XCDs x 96; same-A row-strips go to one XCD.
  int flat = blockIdx.y * 12 + blockIdx.x;
  int f2 = (flat & 7) * 96 + (flat >> 3);
  int col0 = (f2 % 12) * 64, row0 = (f2 / 12) * 64;

  const int KH = K >> 1;
  const int NS = KH / 32;            // 12 (Wo, K=768) or 32 (Wdown, K=2048)
  const bf16* Ag = A + (size_t)(row0 + (tt >> 2)) * K + g * KH + (tt & 3) * 8;
  const bf16* Bg = B + (size_t)(col0 + (tt >> 2)) * K + g * KH + (tt & 3) * 8;

  #pragma unroll
  for (int s = 0; s < 2; ++s) {
    gl2lds16(Ag + s * 32, At[g][s] + tt * 8);
    gl2lds16(Bg + s * 32, Bt[g][s] + tt * 8);
  }

  f32x4 zero = {0.f, 0.f, 0.f, 0.f};
  f32x4 acc[2][2];
  #pragma unroll
  for (int m = 0; m < 2; ++m)
    #pragma unroll
    for (int n = 0; n < 2; ++n) acc[m][n] = zero;

  #define OG_COMPUTE(slot) do {                                              \
    const bf16* at = At[g][slot]; const bf16* bt = Bt[g][slot];              \
    bf16x8 af[2], bb[2];                                                     \
    _Pragma("unroll")                                                        \
    for (int m = 0; m < 2; ++m)                                              \
      af[m] = *(const bf16x8*)(at + (wrow + m * 16 + l15) * 32 + lq * 8);    \
    _Pragma("unroll")                                                        \
    for (int n = 0; n < 2; ++n)                                              \
      bb[n] = *(const bf16x8*)(bt + (wcol + n * 16 + l15) * 32 + lq * 8);    \
    _Pragma("unroll")                                                        \
    for (int m = 0; m < 2; ++m)                                              \
      _Pragma("unroll")                                                      \
      for (int n = 0; n < 2; ++n)                                            \
        acc[m][n] = MFMA16(af[m], bb[n], acc[m][n]);                         \
  } while (0)

  int slot = 0;
  for (int k = 0; k < NS - 1; ++k) {
    WB(2);                        // stage k resident; stage k+1 may be in flight
    if (k + 2 < NS) {
      int ks = (k + 2) * 32;
      int ws = slot + 2; if (ws >= 3) ws -= 3;   // (k+2)%3 == (k-1)%3
      gl2lds16(Ag + ks, At[g][ws] + tt * 8);
      gl2lds16(Bg + ks, Bt[g][ws] + tt * 8);
    }
    OG_COMPUTE(slot);
    slot = (slot == 2) ? 0 : slot + 1;
  }
  WB(0);
  OG_COMPUTE(slot);
  #undef OG_COMPUTE

  // ---- combine K-halves through LDS overlay (16KB over At), then store ----
  __syncthreads();                  // all LDS reads for compute complete
  float* Cl = (float*)&At[0][0][0];
  if (g == 1) {
    #pragma unroll
    for (int m = 0; m < 2; ++m)
      #pragma unroll
      for (int n = 0; n < 2; ++n)
        #pragma unroll
        for (int r = 0; r < 4; ++r)
          Cl[(wrow + m * 16 + lq * 4 + r) * 64 + wcol + n * 16 + l15] = acc[m][n][r];
  }
  __syncthreads();
  if (g == 0) {
    #pragma unroll
    for (int m = 0; m < 2; ++m)
      #pragma unroll
      for (int n = 0; n < 2; ++n)
        #pragma unroll
        for (int r = 0; r < 4; ++r) {
          int row = wrow + m * 16 + lq * 4 + r;
          int col = wcol + n * 16 + l15;
          size_t idx = (size_t)(row0 + row) * N + col0 + col;
          C[idx] = acc[m][n][r] + Cl[row * 64 + col] + R[idx];
        }
  }
}

// ---------------- QKV GEMM + fused RoPE epilogue: ring-4, single barrier ----------------
__global__ __launch_bounds__(256) void gemm_qkv_kernel(const bf16* __restrict__ A,
    const bf16* __restrict__ Wcat, const float* __restrict__ tab,
    bf16* __restrict__ Qh, bf16* __restrict__ Kh, bf16* __restrict__ Vt) {
  __shared__ __align__(16) bf16 At[4][64 * 32];
  __shared__ __align__(16) bf16 Bt[4][128 * 32];
  const int K = DMODEL;
  int t = threadIdx.x, lane = t & 63, wave = t >> 6;
  int l15 = lane & 15, lq = lane >> 4;
  int wrow = (wave >> 1) * 32, wcol = (wave & 1) * 64;
  int row0 = blockIdx.y * 64, col0 = blockIdx.x * 128;
  const bf16* Ag  = A + (size_t)(row0 + (t >> 2)) * K + (t & 3) * 8;
  const bf16* Bg0 = Wcat + (size_t)(col0 + (t >> 2)) * K + (t & 3) * 8;
  const bf16* Bg1 = Bg0 + (size_t)64 * K;
  const int NS = K / 32;   // 24

  #pragma unroll
  for (int s = 0; s < 3; ++s) {
    int ks = s * 32;
    gl2lds16(Ag + ks,  At[s] + t * 8);
    gl2lds16(Bg0 + ks, Bt[s] + t * 8);
    gl2lds16(Bg1 + ks, Bt[s] + 2048 + t * 8);
  }

  f32x4 zero = {0.f, 0.f, 0.f, 0.f};
  f32x4 acc[2][4];
  #pragma unroll
  for (int m = 0; m < 2; ++m)
    #pragma unroll
    for (int n = 0; n < 4; ++n) acc[m][n] = zero;

  #define QK_COMPUTE(slot) do {                                              \
    const bf16* at = At[slot]; const bf16* bt = Bt[slot];                    \
    bf16x8 af[2], bfr[4];                                                    \
    _Pragma("unroll")                                                        \
    for (int m = 0; m < 2; ++m)                                              \
      af[m] = *(const bf16x8*)(at + (wrow + m * 16 + l15) * 32 + lq * 8);    \
    _Pragma("unroll")                                                        \
    for (int n = 0; n < 4; ++n)                                              \
      bfr[n] = *(const bf16x8*)(bt + (wcol + n * 16 + l15) * 32 + lq * 8);   \
    _Pragma("unroll")                                                        \
    for (int m = 0; m < 2; ++m)                                              \
      _Pragma("unroll")                                                      \
      for (int n = 0; n < 4; ++n)                                            \
        acc[m][n] = MFMA16(af[m], bfr[n], acc[m][n]);                        \
  } while (0)

  for (int k = 0; k < NS - 2; ++k) {
    WB(6);
    if (k + 3 < NS) {
      int ks = (k + 3) * 32;
      int ws = (k + 3) & 3;
      gl2lds16(Ag + ks,  At[ws] + t * 8);
      gl2lds16(Bg0 + ks, Bt[ws] + t * 8);
      gl2lds16(Bg1 + ks, Bt[ws] + 2048 + t * 8);
    }
    QK_COMPUTE(k & 3);
  }
  WB(3);
  QK_COMPUTE((NS - 2) & 3);
  WB(0);
  QK_COMPUTE((NS - 1) & 3);
  #undef QK_COMPUTE

  // ---- epilogue: RoPE (Q,K) / transpose-store (V) ----
  int b = row0 >> 11;
  int s0 = (row0 & 2047) + wrow + lq * 4;
  int colw = col0 + wcol;
  if (colw < 768) {
    int h = colw >> 6;
    f32x4 cv[2][2], sv[2][2];
    #pragma unroll
    for (int m = 0; m < 2; ++m)
      #pragma unroll
      for (int jh = 0; jh < 2; ++jh) {
        const float* cp = tab + (jh * 16 + l15) * 2048 + s0 + m * 16;
        cv[m][jh] = *(const f32x4*)cp;
        sv[m][jh] = *(const f32x4*)(cp + 65536);
      }
    #pragma unroll
    for (int m = 0; m < 2; ++m)
      #pragma unroll
      for (int n = 0; n < 4; ++n) {
        float sgn = (n < 2) ? -1.f : 1.f;
        #pragma unroll
        for (int r = 0; r < 4; ++r) {
          float c = cv[m][n & 1][r], si = sv[m][n & 1][r];
          float rp = (acc[m][n][r] * c + sgn * acc[m][n ^ 2][r] * si) * QSCALE;
          Qh[((size_t)(b * NH + h) * SEQ + s0 + m * 16 + r) * 64 + n * 16 + l15] = (bf16)rp;
        }
      }
  } else if (colw < 1024) {
    int kh = (colw - 768) >> 6;
    f32x4 cv[2][2], sv[2][2];
    #pragma unroll
    for (int m = 0; m < 2; ++m)
      #pragma unroll
      for (int jh = 0; jh < 2; ++jh) {
        const float* cp = tab + (jh * 16 + l15) * 2048 + s0 + m * 16;
        cv[m][jh] = *(const f32x4*)cp;
        sv[m][jh] = *(const f32x4*)(cp + 65536);
      }
    #pragma unroll
    for (int m = 0; m < 2; ++m)
      #pragma unroll
      for (int n = 0; n < 4; ++n) {
        float sgn = (n < 2) ? -1.f : 1.f;
        #pragma unroll
        for (int r = 0; r < 4; ++r) {
          float c = cv[m][n & 1][r], si = sv[m][n & 1][r];
          float rp = acc[m][n][r] * c + sgn * acc[m][n ^ 2][r] * si;
          Kh[((size_t)(b * NKV + kh) * SEQ + s0 + m * 16 + r) * 64 + n * 16 + l15] = (bf16)rp;
        }
      }
  } else {
    int vh = (colw - 1024) >> 6;
    #pragma unroll
    for (int m = 0; m < 2; ++m)
      #pragma unroll
      for (int n = 0; n < 4; ++n) {
        bf16x4 pv;
        #pragma unroll
        for (int r = 0; r < 4; ++r) pv[r] = (bf16)acc[m][n][r];
        *(bf16x4*)(Vt + ((size_t)(b * NKV + vh) * 64 + n * 16 + l15) * SEQ + s0 + m * 16) = pv;
      }
  }
}

// ---------------- Gate/up fused GEMM + silu: 256x256 8-phase, fragment-major LDS ----------------
// (round-6 best-measured configuration)
__global__ __launch_bounds__(512, 2) void gemm_gu_kernel(const bf16* __restrict__ A,
    const bf16* __restrict__ W, bf16* __restrict__ H) {
  __shared__ __align__(16) bf16 Als[2 * 2 * 128 * 64];   // 64KB
  __shared__ __align__(16) bf16 Bls[2 * 2 * 128 * 64];   // 64KB
  const int NT = 12;                 // 768 / 64
  int t = threadIdx.x, lane = t & 63, wave = t >> 6;
  int l15 = lane & 15, lq = lane >> 4;
  int lfrag = l15 * 32 + lq * 8;     // lane's chunk offset (bf16) within (m,kk) group
  int wm = wave >> 2, wn = wave & 3;

  // XCD-chunked bijective remap: 256 blocks = 8 XCDs x 32.
  int flat = blockIdx.y * 16 + blockIdx.x;
  int f2 = (flat & 7) * 32 + (flat >> 3);
  int colb = f2 & 15, rowb = f2 >> 4;
  int row0 = rowb * 256, col0w = colb * 256;

  // Fragment-major stage: thread t loads chunks t and t+512 of half h, tile j.
  #define STAGE(G, orow, L, j, h) do {                                       \
    bf16* lb = (L) + ((j) & 1) * 16384 + (h) * 8192 + t * 8;                 \
    const bf16* gb = (G) + (size_t)((orow) + (h) * 128 + ((t >> 7) << 4)     \
                   + ((t >> 2) & 15)) * 768 + (j) * 64                       \
                   + ((t >> 6) & 1) * 32 + (t & 3) * 8;                      \
    gl2lds16(gb, lb);                                                        \
    gl2lds16(gb + (size_t)64 * 768, lb + 4096);                              \
  } while (0)

  // Prologue in steady-state issue order: B(0), A(0), B(1)  (6 stages, 12 loads)
  STAGE(W, col0w, Bls, 0, 0);  STAGE(W, col0w, Bls, 0, 1);
  STAGE(A, row0,  Als, 0, 0);  STAGE(A, row0,  Als, 0, 1);
  STAGE(W, col0w, Bls, 1, 0);  STAGE(W, col0w, Bls, 1, 1);

  f32x4 zero = {0.f, 0.f, 0.f, 0.f};
  f32x4 acc[8][4];
  #pragma unroll
  for (int m = 0; m < 8; ++m)
    #pragma unroll
    for (int n = 0; n < 4; ++n) acc[m][n] = zero;

  WB(4);                             // tile-0 halves landed; B(1) in flight

  for (int j = 0; j < NT; ++j) {
    const bf16* aB = Als + (j & 1) * 16384 + wm * 8192 + lfrag;
    const bf16* bB = Bls + (j & 1) * 16384 + (wn >> 1) * 8192 + (wn & 1) * 4096 + lfrag;
    bf16x8 afr[4][2], bfr[4][2];

    // ---- phase 0: read A m0-3 + B n0-1 (12 ds_reads); stage A0(j+1) ----
    #pragma unroll
    for (int m = 0; m < 4; ++m)
      #pragma unroll
      for (int kk = 0; kk < 2; ++kk)
        afr[m][kk] = *(const bf16x8*)(aB + m * 1024 + kk * 512);
    #pragma unroll
    for (int n = 0; n < 2; ++n)
      #pragma unroll
      for (int kk = 0; kk < 2; ++kk)
        bfr[n][kk] = *(const bf16x8*)(bB + n * 1024 + kk * 512);
    if (j + 1 < NT) STAGE(A, row0, Als, j + 1, 0);
    BAR();
    __builtin_amdgcn_s_setprio(1);
    #pragma unroll
    for (int m = 0; m < 4; ++m)
      #pragma unroll
      for (int n = 0; n < 2; ++n) {
        acc[m][n] = MFMA16(afr[m][0], bfr[n][0], acc[m][n]);
        acc[m][n] = MFMA16(afr[m][1], bfr[n][1], acc[m][n]);
      }
    __builtin_amdgcn_s_setprio(0);
    BAR();

    // ---- phase 1: read B n2-3 (4 ds_reads); stage A1(j+1) ----
    #pragma unroll
    for (int n = 2; n < 4; ++n)
      #pragma unroll
      for (int kk = 0; kk < 2; ++kk)
        bfr[n][kk] = *(const bf16x8*)(bB + n * 1024 + kk * 512);
    if (j + 1 < NT) STAGE(A, row0, Als, j + 1, 1);
    BAR();
    __builtin_amdgcn_s_setprio(1);
    #pragma unroll
    for (int m = 0; m < 4; ++m)
      #pragma unroll
      for (int n = 2; n < 4; ++n) {
        acc[m][n] = MFMA16(afr[m][0], bfr[n][0], acc[m][n]);
        acc[m][n] = MFMA16(afr[m][1], bfr[n][1], acc[m][n]);
      }
    __builtin_amdgcn_s_setprio(0);
    BAR();

    // ---- phase 2: read A m4-7 (8 ds_reads); stage B0(j+2) ----
    #pragma unroll
    for (int m = 0; m < 4; ++m)
      #pragma unroll
      for (int kk = 0; kk < 2; ++kk)
        afr[m][kk] = *(const bf16x8*)(aB + (m + 4) * 1024 + kk * 512);
    if (j + 2 < NT) STAGE(W, col0w, Bls, j + 2, 0);
    BAR();
    __builtin_amdgcn_s_setprio(1);
    #pragma unroll
    for (int m = 0; m < 4; ++m)
      #pragma unroll
      for (int n = 0; n < 2; ++n) {
        acc[m + 4][n] = MFMA16(afr[m][0], bfr[n][0], acc[m + 4][n]);
        acc[m + 4][n] = MFMA16(afr[m][1], bfr[n][1], acc[m + 4][n]);
      }
    __builtin_amdgcn_s_setprio(0);
    BAR();

    // ---- phase 3: stage B1(j+2); MFMA m4-7 x n2-3 ----
    if (j + 2 < NT) STAGE(W, col0w, Bls, j + 2, 1);
    BAR();
    __builtin_amdgcn_s_setprio(1);
    #pragma unroll
    for (int m = 0; m < 4; ++m)
      #pragma unroll
      for (int n = 2; n < 4; ++n) {
        acc[m + 4][n] = MFMA16(afr[m][0], bfr[n][0], acc[m + 4][n]);
        acc[m + 4][n] = MFMA16(afr[m][1], bfr[n][1], acc[m + 4][n]);
      }
    __builtin_amdgcn_s_setprio(0);
    // ---- tile boundary: counted vmcnt + barrier ----
    if (j < NT - 2)       WB(4);     // B(j+2) stages (4 loads) stay in flight
    else if (j == NT - 2) WB(0);     // drain A(NT-1); nothing newer exists
  }
  #undef STAGE

  // ---- epilogue: silu(gate)*up, wave-local pairing acc[m][n] / acc[m][n+2] ----
  int hc0 = colb * 128 + wn * 32;
  #pragma unroll
  for (int m = 0; m < 8; ++m)
    #pragma unroll
    for (int n = 0; n < 2; ++n)
      #pragma unroll
      for (int r = 0; r < 4; ++r) {
        int row = row0 + wm * 128 + m * 16 + lq * 4 + r;
        int col = hc0 + n * 16 + l15;
        float g = acc[m][n][r], u = acc[m][n + 2][r];
        float sg = g / (1.f + __builtin_amdgcn_exp2f(-g * LOG2E));
        H[(size_t)row * FFDIM + col] = (bf16)(sg * u);
      }
}

// ---------------- Flash attention: 4 waves / 64 q-rows, fragment-major K/V, P-pad 72 ----------------
// 768 blocks (32 q-tiles x 24 bh) = 3 blocks/CU.  K/V tiles fragment-major
// (conflict-free ds_read).  P stride 72 bf16 (=36 dwords == 4 mod 32): the
// old stride 80 (40 dw == 8 mod 32) put all 16 l15-lanes in 4 banks (4-way
// conflict on every P write/read); 72 spreads them over 16 banks (2-way=free).
__global__ __launch_bounds__(256) void attn_kernel(const bf16* __restrict__ Qh,
    const bf16* __restrict__ Kh, const bf16* __restrict__ Vt, bf16* __restrict__ out) {
  __shared__ __align__(16) bf16 Kl0[2][64 * 32];
  __shared__ __align__(16) bf16 Kl1[2][64 * 32];
  __shared__ __align__(16) bf16 Vl0[2][64 * 32];
  __shared__ __align__(16) bf16 Vl1[2][64 * 32];
  __shared__ __align__(16) bf16 P[4][16 * 72];

  int idx = blockIdx.x;
  int qt = 31 - (idx / 24);                      // LPT: heaviest first
  int bh = idx % 24;
  int q0blk = qt * 64;
  int b = bh / NH, h = bh % NH;
  int kvh = h / NREP;
  int t = threadIdx.x;
  int lane = t & 63, wave = t >> 6;
  int l15 = lane & 15, lq = lane >> 4;
  int qw = q0blk + wave * 16;
  const bf16* Qb = Qh + (size_t)(b * NH + h) * SEQ * 64;
  const bf16* Kb = Kh + (size_t)(b * NKV + kvh) * SEQ * 64;
  const bf16* Vb = Vt + (size_t)(b * NKV + kvh) * 64 * SEQ;

  bf16x8 bq0 = *(const bf16x8*)(Qb + (size_t)(qw + l15) * 64 + lq * 8);
  bf16x8 bq1 = *(const bf16x8*)(Qb + (size_t)(qw + l15) * 64 + 32 + lq * 8);

  // fragment-major staging source: thread t covers row srow, k-slice scol
  int srow = (t >> 6) * 16 + ((t >> 2) & 15);
  int scol = (t & 3) * 8;
  const bf16* Kg = Kb + (size_t)srow * 64 + scol;
  const bf16* Vg = Vb + (size_t)srow * SEQ + scol;
  bf16* Pw = P[wave];
  int Pwq = l15 * 72, lq8 = lq * 8, lq4 = lq * 4;
  int lfrag = l15 * 32 + lq8;                    // fragment-major read offset
  const int NS = qt + 1;                         // 64-key steps

  #pragma unroll
  for (int s = 0; s < 2; ++s) {
    int ks = (s < NS ? s : NS - 1) * 64;
    gl2lds16(Kg + (size_t)ks * 64,      Kl0[s] + t * 8);
    gl2lds16(Kg + (size_t)ks * 64 + 32, Kl1[s] + t * 8);
    gl2lds16(Vg + ks,                   Vl0[s] + t * 8);
    gl2lds16(Vg + ks + 32,              Vl1[s] + t * 8);
  }

  f32x4 zero = {0.f, 0.f, 0.f, 0.f};
  f32x4 o[4];
  o[0] = zero; o[1] = zero; o[2] = zero; o[3] = zero;
  float l_r = 0.f;

  #define ATTN_STEP(kk, slot) do {                                           \
    int k0 = (kk) * 64;                                                      \
    const bf16* kl0 = Kl0[slot]; const bf16* kl1 = Kl1[slot];                \
    const bf16* vl0 = Vl0[slot]; const bf16* vl1 = Vl1[slot];                \
    f32x4 s[4];                                                              \
    _Pragma("unroll")                                                        \
    for (int c = 0; c < 4; ++c) {                                            \
      bf16x8 ak0 = *(const bf16x8*)(kl0 + c * 512 + lfrag);                  \
      bf16x8 ak1 = *(const bf16x8*)(kl1 + c * 512 + lfrag);                  \
      s[c] = zero;                                                           \
      s[c] = MFMA16(ak0, bq0, s[c]);                                         \
      s[c] = MFMA16(ak1, bq1, s[c]);                                         \
    }                                                                        \
    if (k0 + 63 > qw) {                                                      \
      int qmk = qw + l15 - k0 - lq4;                                         \
      _Pragma("unroll")                                                      \
      for (int c = 0; c < 4; ++c)                                            \
        _Pragma("unroll")                                                    \
        for (int r = 0; r < 4; ++r)                                          \
          if (c * 16 + r > qmk) s[c][r] = -INFINITY;                         \
    }                                                                        \
    _Pragma("unroll")                                                        \
    for (int c = 0; c < 4; ++c) {                                            \
      bf16x4 pe;                                                             \
      _Pragma("unroll")                                                      \
      for (int r = 0; r < 4; ++r) {                                          \
        float e = __builtin_amdgcn_exp2f(s[c][r]);                           \
        l_r += e;                                                            \
        pe[r] = (bf16)e;                                                     \
      }                                                                      \
      *(bf16x4*)(Pw + Pwq + c * 16 + lq4) = pe;                              \
    }                                                                        \
    bf16x8 bp0 = *(const bf16x8*)(Pw + Pwq + lq8);                           \
    bf16x8 bp1 = *(const bf16x8*)(Pw + Pwq + 32 + lq8);                      \
    _Pragma("unroll")                                                        \
    for (int n = 0; n < 4; ++n) {                                            \
      bf16x8 av0 = *(const bf16x8*)(vl0 + n * 512 + lfrag);                  \
      bf16x8 av1 = *(const bf16x8*)(vl1 + n * 512 + lfrag);                  \
      o[n] = MFMA16(av0, bp0, o[n]);                                         \
      o[n] = MFMA16(av1, bp1, o[n]);                                         \
    }                                                                        \
  } while (0)

  for (int k = 0; k < NS - 1; ++k) {
    WB(4);                        // stage k resident (1 newer stage = 4 loads in flight)
    ATTN_STEP(k, k & 1);
    BAR();
    if (k <= NS - 3) {
      int ks = (k + 2) * 64;
      gl2lds16(Kg + (size_t)ks * 64,      Kl0[k & 1] + t * 8);
      gl2lds16(Kg + (size_t)ks * 64 + 32, Kl1[k & 1] + t * 8);
      gl2lds16(Vg + ks,                   Vl0[k & 1] + t * 8);
      gl2lds16(Vg + ks + 32,              Vl1[k & 1] + t * 8);
    }
  }
  {
    WB(0);
    ATTN_STEP(NS - 1, (NS - 1) & 1);
  }
  #undef ATTN_STEP

  float lt = l_r;
  lt += __shfl_xor(lt, 16, 64);
  lt += __shfl_xor(lt, 32, 64);
  float inv = 1.f / lt;
  int q = qw + l15;
  bf16* orow = out + (size_t)(b * SEQ + q) * DMODEL + h * 64;
  #pragma unroll
  for (int n = 0; n < 4; ++n) {
    bf16x4 po;
    #pragma unroll
    for (int r = 0; r < 4; ++r) po[r] = (bf16)(o[n][r] * inv);
    *(bf16x4*)(orow + n * 16 + lq4) = po;
  }
}

extern "C" void kernel_launch(void* const* d_in, const int* in_sizes, int n_in,
                              void* d_out, int out_size, void* d_ws, size_t ws_size,
                              hipStream_t stream) {
  const float* x     = (const float*)d_in[0];
  const float* Wq    = (const float*)d_in[1];
  const float* Wk    = (const float*)d_in[2];
  const float* Wv    = (const float*)d_in[3];
  const float* Wo    = (const float*)d_in[4];
  const float* Wgate = (const float*)d_in[5];
  const float* Wup   = (const float*)d_in[6];
  const float* Wdown = (const float*)d_in[7];
  const float* g1    = (const float*)d_in[8];
  const float* g2    = (const float*)d_in[9];
  float* out = (float*)d_out;

  char* ws = (char*)d_ws;
  size_t off = 0;
  auto alloc = [&](size_t bytes) { size_t o = off; off += (bytes + 255) & ~(size_t)255; return o; };
  size_t o_tab  = alloc((size_t)2 * 32 * 2048 * 4);          // 512KB cos/sin
  size_t o_x1   = alloc((size_t)4096 * 768 * 4);
  size_t o_xn   = alloc((size_t)4096 * 768 * 2);
  size_t o_Qh   = alloc((size_t)2 * 12 * 2048 * 64 * 2);
  size_t o_Kh   = alloc((size_t)2 * 4 * 2048 * 64 * 2);
  size_t o_Vt   = alloc((size_t)2 * 4 * 64 * 2048 * 2);
  size_t o_ao   = alloc((size_t)4096 * 768 * 2);
  size_t o_H    = alloc((size_t)4096 * 2048 * 2);
  size_t o_Wcat = alloc((size_t)1280 * 768 * 2);
  size_t o_Wo   = alloc((size_t)768 * 768 * 2);
  size_t o_Wgu  = alloc((size_t)4096 * 768 * 2);
  size_t o_Wdn  = alloc((size_t)768 * 2048 * 2);
  if (ws_size < off) return;

  float* tab  = (float*)(ws + o_tab);
  float* fx1  = (float*)(ws + o_x1);
  bf16* bxn   = (bf16*)(ws + o_xn);
  bf16* bQh   = (bf16*)(ws + o_Qh);
  bf16* bKh   = (bf16*)(ws + o_Kh);
  bf16* bVt   = (bf16*)(ws + o_Vt);
  bf16* bao   = (bf16*)(ws + o_ao);
  bf16* bH    = (bf16*)(ws + o_H);
  bf16* bWcat = (bf16*)(ws + o_Wcat);
  bf16* bWo   = (bf16*)(ws + o_Wo);
  bf16* bWgu  = (bf16*)(ws + o_Wgu);
  bf16* bWdn  = (bf16*)(ws + o_Wdn);

  Cvt7 c;
  c.s[0] = Wq;    c.d[0] = bWcat;              c.n[0] = 768 * 768;
  c.s[1] = Wk;    c.d[1] = bWcat + 768 * 768;  c.n[1] = 256 * 768;
  c.s[2] = Wv;    c.d[2] = bWcat + 1024 * 768; c.n[2] = 256 * 768;
  c.s[3] = Wo;    c.d[3] = bWo;                c.n[3] = 768 * 768;
  c.s[4] = Wgate; c.d[4] = bWgu;               c.n[4] = 2048 * 768;   // interleaved
  c.s[5] = Wup;   c.d[5] = bWgu;               c.n[5] = 2048 * 768;   // interleaved
  c.s[6] = Wdown; c.d[6] = bWdn;               c.n[6] = 768 * 2048;
  c.tab = tab;
  cvt_all_kernel<<<dim3(256, 8), 256, 0, stream>>>(c);

  // Attention sublayer
  rmsnorm_kernel<<<4096, 192, 0, stream>>>(x, g1, bxn);
  gemm_qkv_kernel<<<dim3(10, 64), 256, 0, stream>>>(bxn, bWcat, tab, bQh, bKh, bVt);
  attn_kernel<<<dim3(768), 256, 0, stream>>>(bQh, bKh, bVt, bao);
  gemm_out_kernel<<<dim3(12, 64), 512, 0, stream>>>(bao, bWo, fx1, x, 768, 768);

  // FFN sublayer
  rmsnorm_kernel<<<4096, 192, 0, stream>>>(fx1, g2, bxn);
  gemm_gu_kernel<<<dim3(16, 16), 512, 0, stream>>>(bxn, bWgu, bH);
  gemm_out_kernel<<<dim3(12, 64), 512, 0, stream>>>(bH, bWdn, out, fx1, 768, 2048);
}